// Round 13
// baseline (46.856 us; speedup 1.0000x reference)
//
#include <hip/hip_runtime.h>

// SmileResampler: out[b,bh,h,w] = lerp over band axis of x at
// iy = clip(bh + clip(ws[b,bh,w],-2,2), 0, 127) * (128/127) - 0.5
// Shapes: x (4,128,256,256) f32, ws (4,128,256) f32, out same as x.
//
// R13: h-axis ownership (weights are h-invariant; out is contiguous in h).
// Block = (b, 4-band group, 16-h chunk), 256 threads = 4 waves.
// Wave v owns band bh = bg*4+v for 16 h x 256 w -> 16 KB contiguous output,
// written as 8 steps x 2 KB appending (DRAM-friendly, vs 256B granules at
// 256KB stride in R5-R12). Weights (r0, r1, frac) computed ONCE per wave
// from ws[b,bh,:] and held in registers for all 256 h.
// Per step: stage x[b, bh0-3..bh0+6, h..h+1, :] (10 bands x 2 rows = 20
// units of 1 KiB; 5 global_load_lds per wave) -> vmcnt(0)+barrier ->
// lerp 8 elems/lane from LDS -> barrier. LDS 20 KB -> 8 blocks/CU
// (grid 2048 = 8/CU resident, 32 waves = 100% occupancy, phases stagger).
// LDS reads: bank = (lane+64j)%32 = lane%32 -> 2-way alias (free).
// XCD-chunked swizzle: halo-sharing bg-neighbors (+-16 bids) same XCD.

#define BH_ 128
#define H_  256
#define W_  256
#define NB   10          // staged bands: 4 output + 3 halo each side
#define CH    2          // h-rows per step
#define HC   16          // h-rows per block
#define NSTEP (HC / CH)  // 8

__global__ __launch_bounds__(256) void smile_kernel(
    const float* __restrict__ x,
    const float* __restrict__ ws,
    float* __restrict__ out)
{
    __shared__ float stg[NB][CH][W_];    // 20 KiB

    const int t    = threadIdx.x;
    const int wv   = t >> 6;             // 0..3
    const int lane = t & 63;

    // XCD-chunked bijective swizzle (nwg = 2048, 8 XCDs, chunk = 256)
    const int bid0 = blockIdx.x;
    const int bid  = (bid0 & 7) * 256 + (bid0 >> 3);

    const int hc = bid & 15;             // 16 h-chunks
    int rem = bid >> 4;
    const int bg = rem & 31;             // 32 band-groups of 4
    const int b  = rem >> 5;
    const int bh0 = bg * 4;
    const int h0  = hc * HC;

    const int bh = bh0 + wv;             // this wave's output band

    // ---- weights once per wave (h-invariant): r0/r1 local rows + frac ----
    const float scale = (float)(128.0 / 127.0);
    const float* __restrict__ wsp = ws + (size_t)(b * BH_ + bh) * W_ + lane;
    int r0[4], r1[4];
    float fr[4];
#pragma unroll
    for (int j = 0; j < 4; ++j) {
        float sc      = fminf(fmaxf(wsp[j * 64], -2.0f), 2.0f);
        float shifted = fminf(fmaxf((float)bh + sc, 0.0f), (float)(BH_ - 1));
        float iy      = fmaf(shifted, scale, -0.5f);
        float i0f     = floorf(iy);
        fr[j]         = iy - i0f;
        int i0        = (int)i0f;
        r0[j] = min(max(i0, 0), BH_ - 1) - (bh0 - 3);   // 0..9
        r1[j] = min(i0 + 1, BH_ - 1) - (bh0 - 3);       // 0..9
    }

    const float* __restrict__ xb = x + (size_t)b * (BH_ * H_ * W_);
    float* __restrict__ outp =
        out + ((size_t)(b * BH_ + bh) * H_ + h0) * W_ + lane;

    for (int st = 0; st < NSTEP; ++st) {
        const int hh = h0 + st * CH;

        // ---- stage 20 row-units (1 KiB each); 5 per wave: u = wv + 4k ----
#pragma unroll
        for (int k = 0; k < 5; ++k) {
            const int u    = wv + 4 * k;        // 0..19
            const int bl   = u >> 1;            // staged-band row 0..9
            const int ch   = u & 1;
            const int band = min(max(bh0 - 3 + bl, 0), BH_ - 1);
            const float* gp = xb + ((size_t)band * H_ + (hh + ch)) * W_ + lane * 4;
            __builtin_amdgcn_global_load_lds(
                (const __attribute__((address_space(1))) void*)gp,
                (__attribute__((address_space(3))) void*)&stg[bl][ch][0],
                16, 0, 0);
        }

        asm volatile("s_waitcnt vmcnt(0)" ::: "memory");
        __builtin_amdgcn_s_barrier();

        // ---- compute: 2 h-rows x 4 cols per lane; 2 KB contiguous/wave ----
#pragma unroll
        for (int ch = 0; ch < CH; ++ch) {
#pragma unroll
            for (int j = 0; j < 4; ++j) {
                const int w = lane + j * 64;
                float x0 = stg[r0[j]][ch][w];
                float x1 = stg[r1[j]][ch][w];
                __builtin_nontemporal_store(
                    fmaf(fr[j], x1 - x0, x0),
                    outp + (size_t)(st * CH + ch) * W_ + j * 64);
            }
        }

        __builtin_amdgcn_s_barrier();   // all reads done before re-stage
    }
}

extern "C" void kernel_launch(void* const* d_in, const int* in_sizes, int n_in,
                              void* d_out, int out_size, void* d_ws, size_t ws_size,
                              hipStream_t stream) {
    const float* x  = (const float*)d_in[0];
    const float* ws = (const float*)d_in[1];
    float* out = (float*)d_out;

    const int grid = 4 * 32 * 16;        // b * band-groups * h-chunks = 2048
    smile_kernel<<<grid, 256, 0, stream>>>(x, ws, out);
}